// Round 1
// baseline (4642.133 us; speedup 1.0000x reference)
//
#include <hip/hip_runtime.h>
#include <hip/hip_bf16.h>

// GIN forward: N=10000 nodes, E=80000 edges, per-node feature block [A=2][C=15][D=64]
// x layout: [n][a][c][d] contiguous -> row r = n*30 + a*15 + c, R=300000 rows of 64.
#define N_NODES   10000
#define N_EDGES   80000
#define R_TOTAL   300000
#define ELEMS     19200000   // R_TOTAL*64
#define NODE_F    1920       // 30*64 floats per node

// ---------------- transpose h[a][d][c][n] -> x[n][a][c][d] ----------------
__global__ void k_transpose(const float* __restrict__ h, float* __restrict__ x) {
    __shared__ float tile[64][65];
    int tn = blockIdx.x;              // n-tile 0..156
    int ac = blockIdx.y;              // 0..29
    int a = ac / 15, c = ac % 15;
    int tx = threadIdx.x & 63, ty = threadIdx.x >> 6;
    int n0 = tn * 64;
    const float* hp = h + ((size_t)a * 64 * 15 + c) * 10000;   // + d*150000 + n
    for (int dd = ty; dd < 64; dd += 4) {
        int n = n0 + tx;
        if (n < N_NODES) tile[dd][tx] = hp[(size_t)dd * 150000 + n];
    }
    __syncthreads();
    for (int nn = ty; nn < 64; nn += 4) {
        int n = n0 + nn;
        if (n < N_NODES) x[((size_t)(n * 30 + ac)) * 64 + tx] = tile[tx][nn];
    }
}

// ---------------- edge scatter: agg[dst] += x[src] (1920 f32 per edge) ----------------
__global__ void k_scatter(const float* __restrict__ x, float* __restrict__ agg,
                          const int* __restrict__ src, const int* __restrict__ dst) {
    int idx = blockIdx.x * blockDim.x + threadIdx.x;    // one float4 per thread
    if (idx >= N_EDGES * 480) return;
    int e = idx / 480;
    int q = idx - e * 480;
    int s = src[e], d = dst[e];
    const float4 v = ((const float4*)(x + (size_t)s * NODE_F))[q];
    float* ap = agg + (size_t)d * NODE_F + q * 4;
    atomicAdd(ap + 0, v.x);
    atomicAdd(ap + 1, v.y);
    atomicAdd(ap + 2, v.z);
    atomicAdd(ap + 3, v.w);
}

__device__ __forceinline__ float lane_bcast(float v, int k) {
    return __builtin_bit_cast(float, __builtin_amdgcn_readlane(__builtin_bit_cast(int, v), k));
}

// ---------------- passA: t = ((1+eps)*x + agg) @ W + b ; channel stats of t ----------------
__global__ __launch_bounds__(256) void k_passA(const float* __restrict__ x,
                                               float* __restrict__ t,  // agg in, t1 out (in-place)
                                               const float* __restrict__ W,
                                               const float* __restrict__ bias,
                                               const float* __restrict__ epsp, int l,
                                               float* __restrict__ ssum, float* __restrict__ ssq) {
    int j = threadIdx.x & 63;
    int wid = threadIdx.x >> 6;
    float w[64];
#pragma unroll
    for (int k = 0; k < 64; k++) w[k] = W[k * 64 + j];
    float bj = bias[j];
    float e1 = 1.0f + epsp[l];
    float s0 = 0.f, s1 = 0.f;
    const int nGroups = R_TOTAL / 4;
    for (int g = blockIdx.x; g < nGroups; g += gridDim.x) {
        size_t base = ((size_t)g * 4 + wid) * 64;
        float zv = fmaf(e1, x[base + j], t[base + j]);
        float acc = bj;
#pragma unroll
        for (int k = 0; k < 64; k++) acc = fmaf(lane_bcast(zv, k), w[k], acc);
        t[base + j] = acc;
        s0 += acc;
        s1 += acc * acc;
    }
    __shared__ float red[2][4][64];
    red[0][wid][j] = s0;
    red[1][wid][j] = s1;
    __syncthreads();
    if (wid == 0) {
        float a = red[0][0][j] + red[0][1][j] + red[0][2][j] + red[0][3][j];
        float b = red[1][0][j] + red[1][1][j] + red[1][2][j] + red[1][3][j];
        atomicAdd(&ssum[j], a);
        atomicAdd(&ssq[j], b);
    }
}

// ---------------- passB: t = relu(bn(t)) @ W + b ; stats ----------------
__global__ __launch_bounds__(256) void k_passB(float* __restrict__ t,  // t1 in, t3 out
                                               const float* __restrict__ W,
                                               const float* __restrict__ bias,
                                               const float* __restrict__ bnsc,
                                               const float* __restrict__ bnsh,
                                               float* __restrict__ ssum, float* __restrict__ ssq) {
    int j = threadIdx.x & 63;
    int wid = threadIdx.x >> 6;
    float w[64];
#pragma unroll
    for (int k = 0; k < 64; k++) w[k] = W[k * 64 + j];
    float bj = bias[j];
    float sc = bnsc[j], sh = bnsh[j];
    float s0 = 0.f, s1 = 0.f;
    const int nGroups = R_TOTAL / 4;
    for (int g = blockIdx.x; g < nGroups; g += gridDim.x) {
        size_t base = ((size_t)g * 4 + wid) * 64;
        float zv = fmaxf(fmaf(t[base + j], sc, sh), 0.f);
        float acc = bj;
#pragma unroll
        for (int k = 0; k < 64; k++) acc = fmaf(lane_bcast(zv, k), w[k], acc);
        t[base + j] = acc;
        s0 += acc;
        s1 += acc * acc;
    }
    __shared__ float red[2][4][64];
    red[0][wid][j] = s0;
    red[1][wid][j] = s1;
    __syncthreads();
    if (wid == 0) {
        float a = red[0][0][j] + red[0][1][j] + red[0][2][j] + red[0][3][j];
        float b = red[1][0][j] + red[1][1][j] + red[1][2][j] + red[1][3][j];
        atomicAdd(&ssum[j], a);
        atomicAdd(&ssq[j], b);
    }
}

// ---------------- BN finalize: scale/shift from sums ----------------
__global__ void k_bnfin(const float* __restrict__ ssum, const float* __restrict__ ssq,
                        const float* __restrict__ g, const float* __restrict__ b,
                        float* __restrict__ scale, float* __restrict__ shift) {
    int j = threadIdx.x;  // 64
    const float invM = 1.0f / (float)R_TOTAL;
    float m = ssum[j] * invM;
    float v = ssq[j] * invM - m * m;
    float sc = g[j] * rsqrtf(v + 1e-5f);
    scale[j] = sc;
    shift[j] = b[j] - m * sc;
}

// ---------------- passC: t = relu(bn(t)); stats of result ----------------
__global__ __launch_bounds__(256) void k_passC(float* __restrict__ t,
                                               const float* __restrict__ sc_,
                                               const float* __restrict__ sh_,
                                               float* __restrict__ ssum, float* __restrict__ ssq) {
    int j = threadIdx.x & 63;
    int wid = threadIdx.x >> 6;
    float sc = sc_[j], sh = sh_[j];
    float s0 = 0.f, s1 = 0.f;
    size_t stride = (size_t)gridDim.x * 256;   // multiple of 64 -> j stable
    for (size_t i = (size_t)blockIdx.x * 256 + threadIdx.x; i < (size_t)ELEMS; i += stride) {
        float v = fmaxf(fmaf(t[i], sc, sh), 0.f);
        t[i] = v;
        s0 += v;
        s1 += v * v;
    }
    __shared__ float red[2][4][64];
    red[0][wid][j] = s0;
    red[1][wid][j] = s1;
    __syncthreads();
    if (wid == 0) {
        float a = red[0][0][j] + red[0][1][j] + red[0][2][j] + red[0][3][j];
        float b = red[1][0][j] + red[1][1][j] + red[1][2][j] + red[1][3][j];
        atomicAdd(&ssum[j], a);
        atomicAdd(&ssq[j], b);
    }
}

// ---------------- passD: t = relu(bn(t)), float4 ----------------
__global__ __launch_bounds__(256) void k_passD(float* __restrict__ t,
                                               const float* __restrict__ sc_,
                                               const float* __restrict__ sh_) {
    float4 sc = ((const float4*)sc_)[threadIdx.x & 15];
    float4 sh = ((const float4*)sh_)[threadIdx.x & 15];
    float4* t4 = (float4*)t;
    const int total4 = ELEMS / 4;
    int stride = gridDim.x * 256;              // multiple of 16 -> j stable
    for (int i = blockIdx.x * 256 + threadIdx.x; i < total4; i += stride) {
        float4 v = t4[i];
        v.x = fmaxf(fmaf(v.x, sc.x, sh.x), 0.f);
        v.y = fmaxf(fmaf(v.y, sc.y, sh.y), 0.f);
        v.z = fmaxf(fmaf(v.z, sc.z, sh.z), 0.f);
        v.w = fmaxf(fmaf(v.w, sc.w, sh.w), 0.f);
        t4[i] = v;
    }
}

// ---------------- pooled[o] += sum_n x[n*1920+o] ----------------
__global__ void k_pooled(const float* __restrict__ x, float* __restrict__ pooled) {
    int o = blockIdx.x * 256 + threadIdx.x;
    if (o >= NODE_F) return;
    int n0 = blockIdx.y * 100;
    float s = 0.f;
    for (int n = n0; n < n0 + 100; n++) s += x[(size_t)n * NODE_F + o];
    atomicAdd(&pooled[o], s);
}

// ---------------- final readout: score + fc -> out[2] ----------------
__global__ void k_final(const float* __restrict__ pooled,   // [3][1920]
                        const float* __restrict__ Wp,       // [3][64][10]
                        const float* __restrict__ bp,       // [3][10]
                        const float* __restrict__ Wfc,      // [15][10]
                        const float* __restrict__ bfc, float* __restrict__ out) {
    __shared__ float oa[2];
    int t = threadIdx.x;
    if (t < 2) oa[t] = 0.f;
    __syncthreads();
    if (t < 300) {
        int a = t / 150, rem = t % 150, c = rem / 10, hh = rem % 10;
        int ac = a * 15 + c;
        float sc_sum = 0.f;
        for (int i = 0; i < 3; i++) {
            float s = bp[i * 10 + hh];
            const float* pp = pooled + i * NODE_F + ac * 64;
            const float* wp = Wp + i * 640 + hh;
            for (int d = 0; d < 64; d++) s += pp[d] * wp[d * 10];
            sc_sum += s;
        }
        atomicAdd(&oa[a], sc_sum * Wfc[c * 10 + hh]);
    }
    __syncthreads();
    if (t < 2) out[t] = oa[t] + bfc[0];
}

extern "C" void kernel_launch(void* const* d_in, const int* in_sizes, int n_in,
                              void* d_out, int out_size, void* d_ws, size_t ws_size,
                              hipStream_t stream) {
    const float* h   = (const float*)d_in[0];
    const float* eps = (const float*)d_in[1];
    const float* W0  = (const float*)d_in[2];
    const float* b0  = (const float*)d_in[3];
    const float* g0  = (const float*)d_in[4];
    const float* be0 = (const float*)d_in[5];
    const float* W1  = (const float*)d_in[6];
    const float* b1  = (const float*)d_in[7];
    const float* ga  = (const float*)d_in[8];
    const float* ba  = (const float*)d_in[9];
    const float* go  = (const float*)d_in[10];
    const float* bo  = (const float*)d_in[11];
    const float* Wp  = (const float*)d_in[12];
    const float* bp  = (const float*)d_in[13];
    const float* Wfc = (const float*)d_in[14];
    const float* bfc = (const float*)d_in[15];
    const int*   src = (const int*)d_in[16];
    const int*   dst = (const int*)d_in[17];
    float* out = (float*)d_out;

    float* bufA = (float*)d_ws;
    float* bufB = bufA + ELEMS;
    float* small = bufB + ELEMS;
    float* bn = small;                 // 6 BN instances x [sum64|sq64|scale64|shift64]
    float* pooled = small + 6 * 256;   // [3][1920]

    hipMemsetAsync(small, 0, (6 * 256 + 3 * NODE_F) * sizeof(float), stream);
    hipMemsetAsync(bufB, 0, (size_t)ELEMS * sizeof(float), stream);

    k_transpose<<<dim3(157, 30), 256, 0, stream>>>(h, bufA);
    k_pooled<<<dim3(8, 100), 256, 0, stream>>>(bufA, pooled);

    float* cur = bufA;
    float* oth = bufB;
    for (int l = 0; l < 2; l++) {
        float* s0s = bn + l * 3 * 256;
        float* s1s = s0s + 256;
        float* s2s = s1s + 256;
        k_scatter<<<(N_EDGES * 480 + 255) / 256, 256, 0, stream>>>(cur, oth, src, dst);
        k_passA<<<2048, 256, 0, stream>>>(cur, oth, W0 + l * 4096, b0 + l * 64, eps, l,
                                          s0s, s0s + 64);
        k_bnfin<<<1, 64, 0, stream>>>(s0s, s0s + 64, g0 + l * 64, be0 + l * 64,
                                      s0s + 128, s0s + 192);
        k_passB<<<2048, 256, 0, stream>>>(oth, W1 + l * 4096, b1 + l * 64,
                                          s0s + 128, s0s + 192, s1s, s1s + 64);
        k_bnfin<<<1, 64, 0, stream>>>(s1s, s1s + 64, ga + l * 64, ba + l * 64,
                                      s1s + 128, s1s + 192);
        k_passC<<<2048, 256, 0, stream>>>(oth, s1s + 128, s1s + 192, s2s, s2s + 64);
        k_bnfin<<<1, 64, 0, stream>>>(s2s, s2s + 64, go + l * 64, bo + l * 64,
                                      s2s + 128, s2s + 192);
        k_passD<<<2048, 256, 0, stream>>>(oth, s2s + 128, s2s + 192);
        k_pooled<<<dim3(8, 100), 256, 0, stream>>>(oth, pooled + (l + 1) * NODE_F);
        if (l == 0) hipMemsetAsync(cur, 0, (size_t)ELEMS * sizeof(float), stream);
        float* tmp = cur; cur = oth; oth = tmp;
    }
    k_final<<<1, 320, 0, stream>>>(pooled, Wp, bp, Wfc, bfc, out);
}

// Round 2
// 868.077 us; speedup vs baseline: 5.3476x; 5.3476x over previous
//
#include <hip/hip_runtime.h>
#include <hip/hip_bf16.h>

// GIN forward: N=10000 nodes, E=80000 edges, per-node feature block [A=2][C=15][D=64]
// x layout: [n][a][c][d] contiguous -> row r = n*30 + a*15 + c, R=300000 rows of 64.
#define N_NODES   10000
#define N_EDGES   80000
#define R_TOTAL   300000
#define ELEMS     19200000   // R_TOTAL*64
#define NODE_F    1920       // 30*64 floats per node

// ---------------- transpose h[a][d][c][n] -> x[n][a][c][d] ----------------
__global__ void k_transpose(const float* __restrict__ h, float* __restrict__ x) {
    __shared__ float tile[64][65];
    int tn = blockIdx.x;              // n-tile 0..156
    int ac = blockIdx.y;              // 0..29
    int a = ac / 15, c = ac % 15;
    int tx = threadIdx.x & 63, ty = threadIdx.x >> 6;
    int n0 = tn * 64;
    const float* hp = h + ((size_t)a * 64 * 15 + c) * 10000;   // + d*150000 + n
    for (int dd = ty; dd < 64; dd += 4) {
        int n = n0 + tx;
        if (n < N_NODES) tile[dd][tx] = hp[(size_t)dd * 150000 + n];
    }
    __syncthreads();
    for (int nn = ty; nn < 64; nn += 4) {
        int n = n0 + nn;
        if (n < N_NODES) x[((size_t)(n * 30 + ac)) * 64 + tx] = tile[tx][nn];
    }
}

// ---------------- CSR build: degree -> scan -> fill ----------------
__global__ void k_deg(const int* __restrict__ dst, int* __restrict__ deg) {
    int e = blockIdx.x * 256 + threadIdx.x;
    if (e < N_EDGES) atomicAdd(&deg[dst[e]], 1);
}

__global__ __launch_bounds__(256) void k_scan(const int* __restrict__ deg,
                                              int* __restrict__ off,
                                              int* __restrict__ cursor) {
    __shared__ int buf[256];
    int t = threadIdx.x;
    int c0 = t * 40;                 // 256*40 = 10240 >= 10000
    int local[40];
    int s = 0;
    for (int i = 0; i < 40; i++) {
        int idx = c0 + i;
        int d = (idx < N_NODES) ? deg[idx] : 0;
        local[i] = d;
        s += d;
    }
    buf[t] = s;
    __syncthreads();
    for (int st = 1; st < 256; st <<= 1) {          // Hillis-Steele inclusive scan
        int v = (t >= st) ? buf[t - st] : 0;
        __syncthreads();
        buf[t] += v;
        __syncthreads();
    }
    int run = buf[t] - s;            // exclusive prefix for this chunk
    for (int i = 0; i < 40; i++) {
        int idx = c0 + i;
        if (idx < N_NODES) {
            off[idx] = run;
            cursor[idx] = run;
            run += local[i];
        }
    }
    if (t == 255) off[N_NODES] = buf[255];
}

__global__ void k_fill(const int* __restrict__ src, const int* __restrict__ dst,
                       int* __restrict__ cursor, int* __restrict__ csr) {
    int e = blockIdx.x * 256 + threadIdx.x;
    if (e < N_EDGES) {
        int p = atomicAdd(&cursor[dst[e]], 1);
        csr[p] = src[e];
    }
}

// ---------------- gather aggregation: agg[n] = sum_{e in in(n)} x[csr_src[e]] ----------------
__global__ __launch_bounds__(256) void k_gather(const float* __restrict__ x,
                                                float* __restrict__ agg,
                                                const int* __restrict__ off,
                                                const int* __restrict__ csr) {
    __shared__ int eds[256];
    int n = blockIdx.x;
    int t = threadIdx.x;
    int e0 = off[n], e1 = off[n + 1];
    float4 acc0 = {0.f, 0.f, 0.f, 0.f};
    float4 acc1 = {0.f, 0.f, 0.f, 0.f};
    for (int base = e0; base < e1; base += 256) {
        int cnt = min(256, e1 - base);
        __syncthreads();
        if (t < cnt) eds[t] = csr[base + t];
        __syncthreads();
        for (int i = 0; i < cnt; i++) {
            const float4* xr = (const float4*)(x + (size_t)eds[i] * NODE_F);
            float4 v = xr[t];
            acc0.x += v.x; acc0.y += v.y; acc0.z += v.z; acc0.w += v.w;
            if (t + 256 < 480) {
                float4 v2 = xr[t + 256];
                acc1.x += v2.x; acc1.y += v2.y; acc1.z += v2.z; acc1.w += v2.w;
            }
        }
    }
    float4* ab = (float4*)(agg + (size_t)n * NODE_F);
    ab[t] = acc0;
    if (t + 256 < 480) ab[t + 256] = acc1;
}

__device__ __forceinline__ float lane_bcast(float v, int k) {
    return __builtin_bit_cast(float, __builtin_amdgcn_readlane(__builtin_bit_cast(int, v), k));
}

// ---------------- passA: t = ((1+eps)*x + agg) @ W + b ; channel stats of t ----------------
__global__ __launch_bounds__(256) void k_passA(const float* __restrict__ x,
                                               float* __restrict__ t,  // agg in, t1 out (in-place)
                                               const float* __restrict__ W,
                                               const float* __restrict__ bias,
                                               const float* __restrict__ epsp, int l,
                                               float* __restrict__ ssum, float* __restrict__ ssq) {
    int j = threadIdx.x & 63;
    int wid = threadIdx.x >> 6;
    float w[64];
#pragma unroll
    for (int k = 0; k < 64; k++) w[k] = W[k * 64 + j];
    float bj = bias[j];
    float e1 = 1.0f + epsp[l];
    float s0 = 0.f, s1 = 0.f;
    const int nGroups = R_TOTAL / 4;
    for (int g = blockIdx.x; g < nGroups; g += gridDim.x) {
        size_t base = ((size_t)g * 4 + wid) * 64;
        float zv = fmaf(e1, x[base + j], t[base + j]);
        float acc = bj;
#pragma unroll
        for (int k = 0; k < 64; k++) acc = fmaf(lane_bcast(zv, k), w[k], acc);
        t[base + j] = acc;
        s0 += acc;
        s1 += acc * acc;
    }
    __shared__ float red[2][4][64];
    red[0][wid][j] = s0;
    red[1][wid][j] = s1;
    __syncthreads();
    if (wid == 0) {
        float a = red[0][0][j] + red[0][1][j] + red[0][2][j] + red[0][3][j];
        float b = red[1][0][j] + red[1][1][j] + red[1][2][j] + red[1][3][j];
        atomicAdd(&ssum[j], a);
        atomicAdd(&ssq[j], b);
    }
}

// ---------------- passB: t = relu(bn(t)) @ W + b ; stats ----------------
__global__ __launch_bounds__(256) void k_passB(float* __restrict__ t,  // t1 in, t3 out
                                               const float* __restrict__ W,
                                               const float* __restrict__ bias,
                                               const float* __restrict__ bnsc,
                                               const float* __restrict__ bnsh,
                                               float* __restrict__ ssum, float* __restrict__ ssq) {
    int j = threadIdx.x & 63;
    int wid = threadIdx.x >> 6;
    float w[64];
#pragma unroll
    for (int k = 0; k < 64; k++) w[k] = W[k * 64 + j];
    float bj = bias[j];
    float sc = bnsc[j], sh = bnsh[j];
    float s0 = 0.f, s1 = 0.f;
    const int nGroups = R_TOTAL / 4;
    for (int g = blockIdx.x; g < nGroups; g += gridDim.x) {
        size_t base = ((size_t)g * 4 + wid) * 64;
        float zv = fmaxf(fmaf(t[base + j], sc, sh), 0.f);
        float acc = bj;
#pragma unroll
        for (int k = 0; k < 64; k++) acc = fmaf(lane_bcast(zv, k), w[k], acc);
        t[base + j] = acc;
        s0 += acc;
        s1 += acc * acc;
    }
    __shared__ float red[2][4][64];
    red[0][wid][j] = s0;
    red[1][wid][j] = s1;
    __syncthreads();
    if (wid == 0) {
        float a = red[0][0][j] + red[0][1][j] + red[0][2][j] + red[0][3][j];
        float b = red[1][0][j] + red[1][1][j] + red[1][2][j] + red[1][3][j];
        atomicAdd(&ssum[j], a);
        atomicAdd(&ssq[j], b);
    }
}

// ---------------- BN finalize: scale/shift from sums ----------------
__global__ void k_bnfin(const float* __restrict__ ssum, const float* __restrict__ ssq,
                        const float* __restrict__ g, const float* __restrict__ b,
                        float* __restrict__ scale, float* __restrict__ shift) {
    int j = threadIdx.x;  // 64
    const float invM = 1.0f / (float)R_TOTAL;
    float m = ssum[j] * invM;
    float v = ssq[j] * invM - m * m;
    float sc = g[j] * rsqrtf(v + 1e-5f);
    scale[j] = sc;
    shift[j] = b[j] - m * sc;
}

// ---------------- passC: t = relu(bn(t)); stats of result ----------------
__global__ __launch_bounds__(256) void k_passC(float* __restrict__ t,
                                               const float* __restrict__ sc_,
                                               const float* __restrict__ sh_,
                                               float* __restrict__ ssum, float* __restrict__ ssq) {
    int j = threadIdx.x & 63;
    int wid = threadIdx.x >> 6;
    float sc = sc_[j], sh = sh_[j];
    float s0 = 0.f, s1 = 0.f;
    size_t stride = (size_t)gridDim.x * 256;   // multiple of 64 -> j stable
    for (size_t i = (size_t)blockIdx.x * 256 + threadIdx.x; i < (size_t)ELEMS; i += stride) {
        float v = fmaxf(fmaf(t[i], sc, sh), 0.f);
        t[i] = v;
        s0 += v;
        s1 += v * v;
    }
    __shared__ float red[2][4][64];
    red[0][wid][j] = s0;
    red[1][wid][j] = s1;
    __syncthreads();
    if (wid == 0) {
        float a = red[0][0][j] + red[0][1][j] + red[0][2][j] + red[0][3][j];
        float b = red[1][0][j] + red[1][1][j] + red[1][2][j] + red[1][3][j];
        atomicAdd(&ssum[j], a);
        atomicAdd(&ssq[j], b);
    }
}

// ---------------- passD: t = relu(bn(t)), float4 ----------------
__global__ __launch_bounds__(256) void k_passD(float* __restrict__ t,
                                               const float* __restrict__ sc_,
                                               const float* __restrict__ sh_) {
    float4 sc = ((const float4*)sc_)[threadIdx.x & 15];
    float4 sh = ((const float4*)sh_)[threadIdx.x & 15];
    float4* t4 = (float4*)t;
    const int total4 = ELEMS / 4;
    int stride = gridDim.x * 256;              // multiple of 16 -> j stable
    for (int i = blockIdx.x * 256 + threadIdx.x; i < total4; i += stride) {
        float4 v = t4[i];
        v.x = fmaxf(fmaf(v.x, sc.x, sh.x), 0.f);
        v.y = fmaxf(fmaf(v.y, sc.y, sh.y), 0.f);
        v.z = fmaxf(fmaf(v.z, sc.z, sh.z), 0.f);
        v.w = fmaxf(fmaf(v.w, sc.w, sh.w), 0.f);
        t4[i] = v;
    }
}

// ---------------- pooled[o] += sum_n x[n*1920+o] ----------------
__global__ void k_pooled(const float* __restrict__ x, float* __restrict__ pooled) {
    int o = blockIdx.x * 256 + threadIdx.x;
    if (o >= NODE_F) return;
    int n0 = blockIdx.y * 100;
    float s = 0.f;
    for (int n = n0; n < n0 + 100; n++) s += x[(size_t)n * NODE_F + o];
    atomicAdd(&pooled[o], s);
}

// ---------------- final readout: score + fc -> out[2] ----------------
__global__ void k_final(const float* __restrict__ pooled,   // [3][1920]
                        const float* __restrict__ Wp,       // [3][64][10]
                        const float* __restrict__ bp,       // [3][10]
                        const float* __restrict__ Wfc,      // [15][10]
                        const float* __restrict__ bfc, float* __restrict__ out) {
    __shared__ float oa[2];
    int t = threadIdx.x;
    if (t < 2) oa[t] = 0.f;
    __syncthreads();
    if (t < 300) {
        int a = t / 150, rem = t % 150, c = rem / 10, hh = rem % 10;
        int ac = a * 15 + c;
        float sc_sum = 0.f;
        for (int i = 0; i < 3; i++) {
            float s = bp[i * 10 + hh];
            const float* pp = pooled + i * NODE_F + ac * 64;
            const float* wp = Wp + i * 640 + hh;
            for (int d = 0; d < 64; d++) s += pp[d] * wp[d * 10];
            sc_sum += s;
        }
        atomicAdd(&oa[a], sc_sum * Wfc[c * 10 + hh]);
    }
    __syncthreads();
    if (t < 2) out[t] = oa[t] + bfc[0];
}

extern "C" void kernel_launch(void* const* d_in, const int* in_sizes, int n_in,
                              void* d_out, int out_size, void* d_ws, size_t ws_size,
                              hipStream_t stream) {
    const float* h   = (const float*)d_in[0];
    const float* eps = (const float*)d_in[1];
    const float* W0  = (const float*)d_in[2];
    const float* b0  = (const float*)d_in[3];
    const float* g0  = (const float*)d_in[4];
    const float* be0 = (const float*)d_in[5];
    const float* W1  = (const float*)d_in[6];
    const float* b1  = (const float*)d_in[7];
    const float* ga  = (const float*)d_in[8];
    const float* ba  = (const float*)d_in[9];
    const float* go  = (const float*)d_in[10];
    const float* bo  = (const float*)d_in[11];
    const float* Wp  = (const float*)d_in[12];
    const float* bp  = (const float*)d_in[13];
    const float* Wfc = (const float*)d_in[14];
    const float* bfc = (const float*)d_in[15];
    const int*   src = (const int*)d_in[16];
    const int*   dst = (const int*)d_in[17];
    float* out = (float*)d_out;

    float* bufA = (float*)d_ws;
    float* bufB = bufA + ELEMS;
    float* small = bufB + ELEMS;
    float* bn = small;                   // 6 BN instances x [sum64|sq64|scale64|shift64]
    float* pooled = small + 6 * 256;     // [3][1920]
    int* ideg   = (int*)(pooled + 3 * NODE_F);   // [10000]
    int* ioff   = ideg + N_NODES;                // [10001]
    int* icur   = ioff + N_NODES + 1;            // [10000]
    int* icsr   = icur + N_NODES;                // [80000]

    // zero: bn stats + pooled + deg histogram (one contiguous region)
    hipMemsetAsync(small, 0,
                   (6 * 256 + 3 * NODE_F) * sizeof(float) + N_NODES * sizeof(int), stream);

    // CSR build (once; reused by both layers)
    k_deg<<<(N_EDGES + 255) / 256, 256, 0, stream>>>(dst, ideg);
    k_scan<<<1, 256, 0, stream>>>(ideg, ioff, icur);
    k_fill<<<(N_EDGES + 255) / 256, 256, 0, stream>>>(src, dst, icur, icsr);

    k_transpose<<<dim3(157, 30), 256, 0, stream>>>(h, bufA);
    k_pooled<<<dim3(8, 100), 256, 0, stream>>>(bufA, pooled);

    float* cur = bufA;
    float* oth = bufB;
    for (int l = 0; l < 2; l++) {
        float* s0s = bn + l * 3 * 256;
        float* s1s = s0s + 256;
        float* s2s = s1s + 256;
        k_gather<<<N_NODES, 256, 0, stream>>>(cur, oth, ioff, icsr);
        k_passA<<<2048, 256, 0, stream>>>(cur, oth, W0 + l * 4096, b0 + l * 64, eps, l,
                                          s0s, s0s + 64);
        k_bnfin<<<1, 64, 0, stream>>>(s0s, s0s + 64, g0 + l * 64, be0 + l * 64,
                                      s0s + 128, s0s + 192);
        k_passB<<<2048, 256, 0, stream>>>(oth, W1 + l * 4096, b1 + l * 64,
                                          s0s + 128, s0s + 192, s1s, s1s + 64);
        k_bnfin<<<1, 64, 0, stream>>>(s1s, s1s + 64, ga + l * 64, ba + l * 64,
                                      s1s + 128, s1s + 192);
        k_passC<<<2048, 256, 0, stream>>>(oth, s1s + 128, s1s + 192, s2s, s2s + 64);
        k_bnfin<<<1, 64, 0, stream>>>(s2s, s2s + 64, go + l * 64, bo + l * 64,
                                      s2s + 128, s2s + 192);
        k_passD<<<2048, 256, 0, stream>>>(oth, s2s + 128, s2s + 192);
        k_pooled<<<dim3(8, 100), 256, 0, stream>>>(oth, pooled + (l + 1) * NODE_F);
        float* tmp = cur; cur = oth; oth = tmp;
    }
    k_final<<<1, 320, 0, stream>>>(pooled, Wp, bp, Wfc, bfc, out);
}